// Round 9
// baseline (235.022 us; speedup 1.0000x reference)
//
#include <hip/hip_runtime.h>
#include <hip/hip_bf16.h>
#include <stdint.h>

#define H_DIM 1024
#define S_DIM 4096
#define B_DIM 4

typedef __bf16 bf16x8 __attribute__((ext_vector_type(8)));
typedef float f32x4 __attribute__((ext_vector_type(4)));
typedef unsigned short u16x4 __attribute__((ext_vector_type(4)));
typedef unsigned short u16x8 __attribute__((ext_vector_type(8)));

__device__ __forceinline__ unsigned short f2bf(float f) {
    union { float f; uint32_t u; } v; v.f = f;
    uint32_t u = v.u;
    uint32_t r = (u + 0x7FFFu + ((u >> 16) & 1u)) >> 16;  // round-to-nearest-even
    return (unsigned short)r;
}
__device__ __forceinline__ float bf2f(unsigned short u) {
    union { uint32_t u; float f; } v; v.u = (uint32_t)u << 16; return v.f;
}

// Clobber-free sync (R7): no "memory" clobber -> no compiler-inserted drains.
__device__ __forceinline__ void gate_vmcnt0() {
    __builtin_amdgcn_sched_barrier(0);
    asm volatile("s_waitcnt vmcnt(0)");
    __builtin_amdgcn_sched_barrier(0);
}
__device__ __forceinline__ void gate_lgkm0() {
    asm volatile("s_waitcnt lgkmcnt(0)");
    __builtin_amdgcn_sched_barrier(0);   // rule #18
}

template <int IMM>
__device__ __forceinline__ bf16x8 ds_read_b128_imm(unsigned addr) {
    bf16x8 r;
    asm volatile("ds_read_b128 %0, %1 offset:%2"
                 : "=v"(r) : "v"(addr), "i"(IMM));
    return r;
}

// X[b][s][h] fp32 -> Xb[b][s][h] bf16  and  XT[b][h][s] bf16 (vectorized)
__global__ __launch_bounds__(256)
void cast_x_kernel(const float* __restrict__ X,
                   unsigned short* __restrict__ Xb,
                   unsigned short* __restrict__ XT) {
    __shared__ float tile[64][65];
    const int b  = blockIdx.z;
    const int h0 = blockIdx.x * 64;
    const int s0 = blockIdx.y * 64;
    const int tx = threadIdx.x;   // 0..15
    const int ty = threadIdx.y;   // 0..15
#pragma unroll
    for (int j = 0; j < 4; ++j) {
        int s = ty + 16 * j;
        f32x4 v = *(const f32x4*)&X[((size_t)b * S_DIM + s0 + s) * H_DIM + h0 + tx * 4];
        u16x4 o;
#pragma unroll
        for (int k = 0; k < 4; ++k) {
            tile[s][tx * 4 + k] = v[k];
            o[k] = f2bf(v[k]);
        }
        *(u16x4*)&Xb[((size_t)b * S_DIM + s0 + s) * H_DIM + h0 + tx * 4] = o;
    }
    __syncthreads();
#pragma unroll
    for (int j = 0; j < 4; ++j) {
        int hh = ty + 16 * j;
        u16x4 o;
#pragma unroll
        for (int k = 0; k < 4; ++k)
            o[k] = f2bf(tile[tx * 4 + k][hh]);
        *(u16x4*)&XT[((size_t)b * H_DIM + h0 + hh) * S_DIM + s0 + tx * 4] = o;
    }
}

// W[o][h'] fp32 -> WT[h'][o] bf16 (small: 4 MB read)
__global__ void cast_w_kernel(const float* __restrict__ W,
                              unsigned short* __restrict__ WT) {
    __shared__ float tile[32][33];
    const int b0 = blockIdx.x * 32;
    const int o0 = blockIdx.y * 32;
    const int tx = threadIdx.x;
    const int ty = threadIdx.y;
#pragma unroll
    for (int i = 0; i < 4; ++i) {
        int o = ty + 8 * i;
        tile[o][tx] = W[(size_t)(o0 + o) * H_DIM + b0 + tx];
    }
    __syncthreads();
#pragma unroll
    for (int i = 0; i < 4; ++i) {
        int bb = ty + 8 * i;
        WT[(size_t)(b0 + bb) * H_DIM + o0 + tx] = f2bf(tile[tx][bb]);
    }
}

// Sum NSPLIT bf16 partials -> bf16. 16B/lane both directions.
template <int NSPLIT>
__global__ void reduce_cast_u16_kernel(const unsigned short* __restrict__ P,
                                       unsigned short* __restrict__ Out,
                                       size_t sSplit) {
    size_t i = ((size_t)blockIdx.x * blockDim.x + threadIdx.x) * 8;
    float s[8] = {0.f, 0.f, 0.f, 0.f, 0.f, 0.f, 0.f, 0.f};
#pragma unroll
    for (int sp = 0; sp < NSPLIT; ++sp) {
        u16x8 u = *(const u16x8*)&P[(size_t)sp * sSplit + i];
#pragma unroll
        for (int k = 0; k < 8; ++k) s[k] += bf2f(u[k]);
    }
    u16x8 o;
#pragma unroll
    for (int k = 0; k < 8; ++k) o[k] = f2bf(s[k]);
    *(u16x8*)&Out[i] = o;
}

// ============================================================================
// R9: 2-BLOCKS/CU GEMM (TLP via register diet). C[M,N] = A[M,K] @ Bt[N,K]^T.
//
// R8 post-mortem: coalesced staging was the wall (43 µs, 800 TF, MfmaUtil 30).
// Remaining limiter: acc[8][4]=128 regs + 92 VGPR = 220/wave on the unified
// file -> 2 waves/SIMD -> 1 block/CU -> every gate/lgkm0/barrier idles the CU.
// R9: 256x128 tile, 8 waves (4M x 2N), wave-tile 64x64 -> acc 64 regs, total
// <=128 -> 4 waves/SIMD = 2 blocks/CU (launch_bounds(512,4)). The co-resident
// block covers all intra-block stalls (m114/m97 mechanism, proven 874 TF).
//
// Layout (R8, proven): per operand per buffer [row][64B row of 32 k-elems],
// A 16 KB (256 rows) + B 8 KB (128 rows) = 24 KB/buffer; double-buffered =
// 49152 B LDS (2 blocks x 48 KB = 96 KB < 160). Staging wave-instr = 16 rows
// x 64 B, lane l -> row l>>2, k8-chunk (l&3)^((l>>3)&3) (slot perm; 4-lane
// groups read one full 64B line = coalescing minimum; LDS dest linear,
// swizzle in SOURCE address — rule #21/m173). ds_read slot = q^((col>>1)&3),
// 2-way bank alias = free (m136).
//
// Schedule per K-tile n (BK=32, distance-1 prefetch, m97 form):
//   gate vmcnt(0)            [stage(n) landed — issued 1 full tile ago]
//   s_barrier
//   stage(n+1) into buf (n+1)&1   [3 loads/thread; WAR-safe: that buf's
//     readers (tile n-1) all passed their lgkm0 before this barrier]
//   8+4 ds_read_b128 (av[0..3]x2? no: av[4] A-frags, bv[4] B-frags)
//   lgkm0; prio1; 16x mfma_16x16x32; prio0
// Requires M mult of 256, N mult of 128, T = Ksub/32 >= 1.
// ============================================================================
template <typename OutT, int NSPLIT>
__global__ __launch_bounds__(512, 4)
void gemm_r9_kernel(const unsigned short* __restrict__ A,
                    const unsigned short* __restrict__ Bt,
                    OutT* __restrict__ C,
                    int K, int lda, int ldb, int ldc,
                    size_t sA, size_t sB, size_t sC, size_t sSplit) {
    extern __shared__ char smem_raw[];
    // stage: [buf(2)][A 16KB | B 8KB] = 49152 B; epi overlays post-sync
    // (float[8][1088] = 34816 B).

    const int tid  = threadIdx.x;
    const int w    = tid >> 6;       // 0..7
    const int lane = tid & 63;
    const int wm   = w & 3;          // M quarter: rows wm*64
    const int wn   = w >> 2;         // N half: cols wn*64
    const int q    = lane >> 4;      // 0..3 (k8)
    const int col  = lane & 15;

    const int tileM = blockIdx.x * 256;
    const int tileN = blockIdx.y * 128;
    const int bz   = blockIdx.z / NSPLIT;
    const int sp   = blockIdx.z % NSPLIT;
    const int Ksub = K / NSPLIT;
    const int T    = Ksub >> 5;      // K-tiles of 32

    const unsigned short* Ab = A + sA * bz + (size_t)sp * Ksub;
    const unsigned short* Bb = Bt + sB * bz + (size_t)sp * Ksub;

    auto lds3 = (__attribute__((address_space(3))) char*)&smem_raw[0];
    const unsigned ldsBase = (unsigned)(size_t)lds3;

    // fragment read bases: element (row, k=q*8+e) at byte row*64 + slot*16,
    // slot = q ^ ((row>>1)&3) = q ^ ((col>>1)&3) (wm*64, mf*16 ≡ 0 mod 8).
    const int slot = q ^ ((col >> 1) & 3);
    const unsigned aBase = ldsBase + (unsigned)(wm * 4096 + col * 64 + slot * 16);
    const unsigned bBase = ldsBase + 16384u + (unsigned)(wn * 4096 + col * 64 + slot * 16);
    // imm on top: mf*1024 (A, <=3072) / nf*1024 (B, <=3072); buf adds 24576.

    // staging: A row-groups g=2w+j (16 of 16 rows), B group g=w (8 groups).
    const int lrow = lane >> 2;
    const int koff = ((lane & 3) ^ ((lane >> 3) & 3)) * 8;
    const unsigned short* pA[2];
    unsigned dA[2];
#pragma unroll
    for (int j = 0; j < 2; ++j) {
        int g = 2 * w + j;
        pA[j] = Ab + (size_t)(tileM + g * 16 + lrow) * lda + koff;
        dA[j] = (unsigned)(g * 1024);
    }
    const unsigned short* pB = Bb + (size_t)(tileN + w * 16 + lrow) * ldb + koff;
    const unsigned dB = 16384u + (unsigned)(w * 1024);

    auto stage = [&](int tgt) {
        const unsigned bo = (unsigned)(tgt & 1) * 24576u;
#pragma unroll
        for (int j = 0; j < 2; ++j)
            __builtin_amdgcn_global_load_lds(
                (const __attribute__((address_space(1))) void*)(pA[j] + tgt * 32),
                (__attribute__((address_space(3))) void*)(lds3 + bo + dA[j]),
                16, 0, 0);
        __builtin_amdgcn_global_load_lds(
            (const __attribute__((address_space(1))) void*)(pB + tgt * 32),
            (__attribute__((address_space(3))) void*)(lds3 + bo + dB),
            16, 0, 0);
    };

    f32x4 acc[4][4];
#pragma unroll
    for (int r = 0; r < 4; ++r)
#pragma unroll
        for (int c = 0; c < 4; ++c)
            acc[r][c] = (f32x4){0.f, 0.f, 0.f, 0.f};

    stage(0);

    for (int n = 0; n < T; ++n) {
        gate_vmcnt0();                   // stage(n) landed (issued 1 tile ago)
        __builtin_amdgcn_s_barrier();
        if (n + 1 < T) stage(n + 1);

        const unsigned aAddr = aBase + (unsigned)((n & 1) * 24576);
        const unsigned bAddr = bBase + (unsigned)((n & 1) * 24576);
        bf16x8 av[4], bv[4];
        av[0] = ds_read_b128_imm<0>(aAddr);
        av[1] = ds_read_b128_imm<1024>(aAddr);
        av[2] = ds_read_b128_imm<2048>(aAddr);
        av[3] = ds_read_b128_imm<3072>(aAddr);
        bv[0] = ds_read_b128_imm<0>(bAddr);
        bv[1] = ds_read_b128_imm<1024>(bAddr);
        bv[2] = ds_read_b128_imm<2048>(bAddr);
        bv[3] = ds_read_b128_imm<3072>(bAddr);
        gate_lgkm0();
        __builtin_amdgcn_s_setprio(1);
#pragma unroll
        for (int mf = 0; mf < 4; ++mf)
#pragma unroll
            for (int nf = 0; nf < 4; ++nf)
                acc[mf][nf] = __builtin_amdgcn_mfma_f32_16x16x32_bf16(
                    av[mf], bv[nf], acc[mf][nf], 0, 0, 0);
        __builtin_amdgcn_s_setprio(0);
    }

    // epilogue: per-wave LDS transpose (stride 68 floats), coalesced stores.
    OutT* Cb = C + sC * bz + sSplit * sp;
    __syncthreads();   // full drain once; epi overlays stage region
    float* lws = (float*)(smem_raw) + (size_t)w * 1088;
    const int lr = lane >> 4;
    const int lc = lane & 15;
#pragma unroll
    for (int mf = 0; mf < 4; ++mf) {
#pragma unroll
        for (int nf = 0; nf < 4; ++nf)
#pragma unroll
            for (int v = 0; v < 4; ++v)
                lws[(q * 4 + v) * 68 + nf * 16 + col] = acc[mf][nf][v];
#pragma unroll
        for (int p = 0; p < 4; ++p) {
            f32x4 t = *(const f32x4*)&lws[(p * 4 + lr) * 68 + lc * 4];
            int row  = tileM + wm * 64 + mf * 16 + p * 4 + lr;
            int colg = tileN + wn * 64 + lc * 4;
            if constexpr (sizeof(OutT) == 2) {
                u16x4 u;
                u[0] = f2bf(t[0]); u[1] = f2bf(t[1]);
                u[2] = f2bf(t[2]); u[3] = f2bf(t[3]);
                *(u16x4*)&Cb[(size_t)row * ldc + colg] = u;
            } else {
                *(f32x4*)&Cb[(size_t)row * ldc + colg] = t;
            }
        }
        // per-wave epi slice is private; no inter-mf barrier needed
    }
}

extern "C" void kernel_launch(void* const* d_in, const int* in_sizes, int n_in,
                              void* d_out, int out_size, void* d_ws, size_t ws_size,
                              hipStream_t stream) {
    const float* X = (const float*)d_in[0];   // [4,4096,1024]
    const float* W = (const float*)d_in[1];   // [1024,1024]
    float* out = (float*)d_out;               // [4,4096,1024] fp32

    char* ws = (char*)d_ws;
    unsigned short* Xb = (unsigned short*)(ws);              // 33,554,432  [b][s][h]
    unsigned short* XT = (unsigned short*)(ws + 33554432);   // 33,554,432  [b][h][s]
    unsigned short* WT = (unsigned short*)(ws + 67108864);   //  2,097,152  [h'][o]
    unsigned short* G  = (unsigned short*)(ws + 69206016);   //  8,388,608  [b][o][h]
    unsigned short* MT = (unsigned short*)(ws + 77594624);   //  8,388,608  [b][h''][h]
    // Scratch (reused serially): Gpart then MTpart, each [sp(4)][b][1024][1024]
    unsigned short* Gpart  = (unsigned short*)(ws + 85983232); // 16,777,216
    unsigned short* MTpart = (unsigned short*)(ws + 85983232); // 16,777,216
    // high-water: 102,760,448 bytes < 153,092,096 proven available

    const size_t sBH = (size_t)B_DIM * H_DIM * H_DIM;

    // 1) casts + transposes
    cast_x_kernel<<<dim3(H_DIM / 64, S_DIM / 64, B_DIM), dim3(16, 16), 0, stream>>>(X, Xb, XT);
    cast_w_kernel<<<dim3(H_DIM / 32, H_DIM / 32, 1), dim3(32, 8), 0, stream>>>(W, WT);

    // 2) G_b = XT_b @ XT_b^T, full symmetric, split-K=4 (Ksub=1024, T=32).
    //    grid (4,8,16) = 512 blocks = 2/CU.
    gemm_r9_kernel<unsigned short, 4><<<dim3(4, 8, B_DIM * 4), 512, 49152, stream>>>(
        XT, XT, Gpart, S_DIM, S_DIM, S_DIM, H_DIM,
        (size_t)H_DIM * S_DIM, (size_t)H_DIM * S_DIM, (size_t)H_DIM * H_DIM, sBH);
    reduce_cast_u16_kernel<4><<<dim3(sBH / 8 / 256), 256, 0, stream>>>(Gpart, G, sBH);

    // 3) MT_b = G_b @ WT^T, split-K=4 (Ksub=256, T=8), 512 blocks
    gemm_r9_kernel<unsigned short, 4><<<dim3(4, 8, B_DIM * 4), 512, 49152, stream>>>(
        G, WT, MTpart, H_DIM, H_DIM, H_DIM, H_DIM,
        (size_t)H_DIM * H_DIM, (size_t)0, (size_t)H_DIM * H_DIM, sBH);
    reduce_cast_u16_kernel<4><<<dim3(sBH / 8 / 256), 256, 0, stream>>>(MTpart, MT, sBH);

    // 4) att_b = Xb_b @ MT_b^T  [4096x1024], K=1024 (T=32), fp32 out.
    //    grid (16,8,4) = 512 blocks = 2/CU.
    gemm_r9_kernel<float, 1><<<dim3(S_DIM / 256, H_DIM / 128, B_DIM), 512, 49152, stream>>>(
        Xb, MT, out, H_DIM, H_DIM, H_DIM, H_DIM,
        (size_t)S_DIM * H_DIM, (size_t)H_DIM * H_DIM, (size_t)S_DIM * H_DIM, 0);
}

// Round 10
// 231.946 us; speedup vs baseline: 1.0133x; 1.0133x over previous
//
#include <hip/hip_runtime.h>
#include <hip/hip_bf16.h>
#include <stdint.h>

#define H_DIM 1024
#define S_DIM 4096
#define B_DIM 4

typedef __bf16 bf16x8 __attribute__((ext_vector_type(8)));
typedef float f32x4 __attribute__((ext_vector_type(4)));
typedef unsigned short u16x4 __attribute__((ext_vector_type(4)));
typedef unsigned short u16x8 __attribute__((ext_vector_type(8)));

__device__ __forceinline__ unsigned short f2bf(float f) {
    union { float f; uint32_t u; } v; v.f = f;
    uint32_t u = v.u;
    uint32_t r = (u + 0x7FFFu + ((u >> 16) & 1u)) >> 16;  // round-to-nearest-even
    return (unsigned short)r;
}
__device__ __forceinline__ float bf2f(unsigned short u) {
    union { uint32_t u; float f; } v; v.u = (uint32_t)u << 16; return v.f;
}

// Clobber-free sync (R7): no "memory" clobber -> no compiler-inserted drains.
__device__ __forceinline__ void gate_vmcnt8() {
    __builtin_amdgcn_sched_barrier(0);
    asm volatile("s_waitcnt vmcnt(8)");
    __builtin_amdgcn_sched_barrier(0);
}
__device__ __forceinline__ void gate_vmcnt4() {
    __builtin_amdgcn_sched_barrier(0);
    asm volatile("s_waitcnt vmcnt(4)");
    __builtin_amdgcn_sched_barrier(0);
}
__device__ __forceinline__ void gate_vmcnt0() {
    __builtin_amdgcn_sched_barrier(0);
    asm volatile("s_waitcnt vmcnt(0)");
    __builtin_amdgcn_sched_barrier(0);
}
__device__ __forceinline__ void gate_lgkm0() {
    asm volatile("s_waitcnt lgkmcnt(0)");
    __builtin_amdgcn_sched_barrier(0);   // rule #18
}

template <int IMM>
__device__ __forceinline__ bf16x8 ds_read_b128_imm(unsigned addr) {
    bf16x8 r;
    asm volatile("ds_read_b128 %0, %1 offset:%2"
                 : "=v"(r) : "v"(addr), "i"(IMM));
    return r;
}

// X[b][s][h] fp32 -> Xb[b][s][h] bf16  and  XT[b][h][s] bf16 (vectorized)
__global__ __launch_bounds__(256)
void cast_x_kernel(const float* __restrict__ X,
                   unsigned short* __restrict__ Xb,
                   unsigned short* __restrict__ XT) {
    __shared__ float tile[64][65];
    const int b  = blockIdx.z;
    const int h0 = blockIdx.x * 64;
    const int s0 = blockIdx.y * 64;
    const int tx = threadIdx.x;   // 0..15
    const int ty = threadIdx.y;   // 0..15
#pragma unroll
    for (int j = 0; j < 4; ++j) {
        int s = ty + 16 * j;
        f32x4 v = *(const f32x4*)&X[((size_t)b * S_DIM + s0 + s) * H_DIM + h0 + tx * 4];
        u16x4 o;
#pragma unroll
        for (int k = 0; k < 4; ++k) {
            tile[s][tx * 4 + k] = v[k];
            o[k] = f2bf(v[k]);
        }
        *(u16x4*)&Xb[((size_t)b * S_DIM + s0 + s) * H_DIM + h0 + tx * 4] = o;
    }
    __syncthreads();
#pragma unroll
    for (int j = 0; j < 4; ++j) {
        int hh = ty + 16 * j;
        u16x4 o;
#pragma unroll
        for (int k = 0; k < 4; ++k)
            o[k] = f2bf(tile[tx * 4 + k][hh]);
        *(u16x4*)&XT[((size_t)b * H_DIM + h0 + hh) * S_DIM + s0 + tx * 4] = o;
    }
}

// W[o][h'] fp32 -> WT[h'][o] bf16 (small: 4 MB read)
__global__ void cast_w_kernel(const float* __restrict__ W,
                              unsigned short* __restrict__ WT) {
    __shared__ float tile[32][33];
    const int b0 = blockIdx.x * 32;
    const int o0 = blockIdx.y * 32;
    const int tx = threadIdx.x;
    const int ty = threadIdx.y;
#pragma unroll
    for (int i = 0; i < 4; ++i) {
        int o = ty + 8 * i;
        tile[o][tx] = W[(size_t)(o0 + o) * H_DIM + b0 + tx];
    }
    __syncthreads();
#pragma unroll
    for (int i = 0; i < 4; ++i) {
        int bb = ty + 8 * i;
        WT[(size_t)(b0 + bb) * H_DIM + o0 + tx] = f2bf(tile[tx][bb]);
    }
}

// Sum NSPLIT bf16 partials -> bf16. 16B/lane both directions.
template <int NSPLIT>
__global__ void reduce_cast_u16_kernel(const unsigned short* __restrict__ P,
                                       unsigned short* __restrict__ Out,
                                       size_t sSplit) {
    size_t i = ((size_t)blockIdx.x * blockDim.x + threadIdx.x) * 8;
    float s[8] = {0.f, 0.f, 0.f, 0.f, 0.f, 0.f, 0.f, 0.f};
#pragma unroll
    for (int sp = 0; sp < NSPLIT; ++sp) {
        u16x8 u = *(const u16x8*)&P[(size_t)sp * sSplit + i];
#pragma unroll
        for (int k = 0; k < 8; ++k) s[k] += bf2f(u[k]);
    }
    u16x8 o;
#pragma unroll
    for (int k = 0; k < 8; ++k) o[k] = f2bf(s[k]);
    *(u16x8*)&Out[i] = o;
}

// ============================================================================
// R10: DEEP-PREFETCH GEMM (R8 geometry + quad-buffer distance-3 pipeline).
// C[M,N] = A[M,K] @ Bt[N,K]^T  (bf16 in, fp32 accum, OutT out)
//
// R8 (coalesced staging) removed the TA wall -> 800 TF. R9 (TLP) regressed ->
// latency exposure remains but block-interleave doesn't cover it. R10 tests
// the depth axis on top of the coalesced layout: BK=32, FOUR 32KB buffers
// (128 KB LDS), prefetch distance 3 (~3 bodies ~5000 cyc in flight), vmcnt
// floor 8 until the 2-tile tail.
//
// Geometry: 256x256 tile, 512 threads = 8 waves (2M x 4N), wave-tile 128x64
// = 8x4 frags of v_mfma_f32_16x16x32_bf16 (acc 128 regs; 1 block/CU).
// LDS per buffer: A [256 rows][64B] 16KB @0, B 16KB @16384; buf stride 32768.
// Staging (R8-proven): wave-instr = 16 rows x 64B; lane l -> row l>>2,
// k8-chunk (l&3)^((l>>3)&3) (slot perm; 4-lane groups = one full 64B line;
// LDS dest linear — swizzle in SOURCE addr, rule #21/m173). 4 loads/thread
// per tile (2 A-rowgroups + 2 B-rowgroups, g=2w+j).
// ds_read: slot = q^((col>>1)&3) — per-thread constant; 2-way alias free.
//
// Body n:  gate [n+2<T: vmcnt(8) | n+1<T: vmcnt(4) | vmcnt(0)]
//          s_barrier
//          if (n+3<T) stage(n+3, (n+3)&3)   [== buf (n-1)&3; WAR-safe: its
//            readers (tile n-1) passed lgkm0 before their barrier-n arrival]
//          12x ds_read_b128 (av[8], bv[4]); lgkm0; prio1; 32 MFMA; prio0
// Gate audit (4 loads/thread/tile, prologue stages 0,1,2): at gate of tile n
// outstanding = tiles n..min(n+2,T-1) -> 12/8/4 -> drain oldest 4 exactly.
// Requires M,N multiples of 256; works for any T >= 1.
// ============================================================================
template <typename OutT, int NSPLIT>
__global__ __launch_bounds__(512, 2)
void gemm_d10_kernel(const unsigned short* __restrict__ A,
                     const unsigned short* __restrict__ Bt,
                     OutT* __restrict__ C,
                     int K, int lda, int ldb, int ldc,
                     size_t sA, size_t sB, size_t sC, size_t sSplit) {
    extern __shared__ char smem_raw[];
    // stage: [buf(4)][A 16KB | B 16KB] = 131072 B; epi overlays post-sync.

    const int tid  = threadIdx.x;
    const int w    = tid >> 6;       // 0..7
    const int lane = tid & 63;
    const int wm   = w & 1;          // M half: rows wm*128
    const int wn   = w >> 1;         // N quarter: cols wn*64
    const int q    = lane >> 4;      // 0..3 (k8)
    const int col  = lane & 15;

    const int tileM = blockIdx.x * 256;
    const int tileN = blockIdx.y * 256;
    const int bz   = blockIdx.z / NSPLIT;
    const int sp   = blockIdx.z % NSPLIT;
    const int Ksub = K / NSPLIT;
    const int T    = Ksub >> 5;      // K-tiles of 32

    const unsigned short* Ab = A + sA * bz + (size_t)sp * Ksub;
    const unsigned short* Bb = Bt + sB * bz + (size_t)sp * Ksub;

    auto lds3 = (__attribute__((address_space(3))) char*)&smem_raw[0];
    const unsigned ldsBase = (unsigned)(size_t)lds3;

    // fragment read bases: element (row, k=q*8+e) at byte row*64 + slot*16,
    // slot = q ^ ((row>>1)&3) = q ^ ((col>>1)&3)  (wm*128, wn*64, *16 ≡0 mod 8)
    const int slot = q ^ ((col >> 1) & 3);
    const unsigned aBase = ldsBase + (unsigned)(wm * 8192 + col * 64 + slot * 16);
    const unsigned bBase = ldsBase + 16384u + (unsigned)(wn * 4096 + col * 64 + slot * 16);
    // imm on top: mf*1024 (A, <=7168) / nf*1024 (B, <=3072); buf adds 32768*b.

    // staging: row-groups g = 2w+j (16 groups of 16 rows) for A and for B.
    const int lrow = lane >> 2;
    const int koff = ((lane & 3) ^ ((lane >> 3) & 3)) * 8;
    const unsigned short* pA[2];
    const unsigned short* pB[2];
    unsigned dR[2];
#pragma unroll
    for (int j = 0; j < 2; ++j) {
        int g = 2 * w + j;
        pA[j] = Ab + (size_t)(tileM + g * 16 + lrow) * lda + koff;
        pB[j] = Bb + (size_t)(tileN + g * 16 + lrow) * ldb + koff;
        dR[j] = (unsigned)(g * 1024);
    }
    auto stage = [&](int tgt) {
        const unsigned bo = (unsigned)(tgt & 3) * 32768u;
#pragma unroll
        for (int j = 0; j < 2; ++j)
            __builtin_amdgcn_global_load_lds(
                (const __attribute__((address_space(1))) void*)(pA[j] + tgt * 32),
                (__attribute__((address_space(3))) void*)(lds3 + bo + dR[j]),
                16, 0, 0);
#pragma unroll
        for (int j = 0; j < 2; ++j)
            __builtin_amdgcn_global_load_lds(
                (const __attribute__((address_space(1))) void*)(pB[j] + tgt * 32),
                (__attribute__((address_space(3))) void*)(lds3 + bo + 16384u + dR[j]),
                16, 0, 0);
    };

    f32x4 acc[8][4];
#pragma unroll
    for (int r = 0; r < 8; ++r)
#pragma unroll
        for (int c = 0; c < 4; ++c)
            acc[r][c] = (f32x4){0.f, 0.f, 0.f, 0.f};

    // prologue: tiles 0,1,2 into bufs 0,1,2 (consumption order)
    stage(0);
    if (T > 1) stage(1);
    if (T > 2) stage(2);

    for (int n = 0; n < T; ++n) {
        if (n + 2 < T)      gate_vmcnt8();   // tiles n+1,n+2 stay in flight
        else if (n + 1 < T) gate_vmcnt4();
        else                gate_vmcnt0();
        __builtin_amdgcn_s_barrier();
        if (n + 3 < T) stage(n + 3);

        const unsigned aAddr = aBase + (unsigned)((n & 3) << 15);
        const unsigned bAddr = bBase + (unsigned)((n & 3) << 15);
        bf16x8 av[8], bv[4];
        av[0] = ds_read_b128_imm<0>(aAddr);
        av[1] = ds_read_b128_imm<1024>(aAddr);
        av[2] = ds_read_b128_imm<2048>(aAddr);
        av[3] = ds_read_b128_imm<3072>(aAddr);
        av[4] = ds_read_b128_imm<4096>(aAddr);
        av[5] = ds_read_b128_imm<5120>(aAddr);
        av[6] = ds_read_b128_imm<6144>(aAddr);
        av[7] = ds_read_b128_imm<7168>(aAddr);
        bv[0] = ds_read_b128_imm<0>(bAddr);
        bv[1] = ds_read_b128_imm<1024>(bAddr);
        bv[2] = ds_read_b128_imm<2048>(bAddr);
        bv[3] = ds_read_b128_imm<3072>(bAddr);
        gate_lgkm0();
        __builtin_amdgcn_s_setprio(1);
#pragma unroll
        for (int mf = 0; mf < 8; ++mf)
#pragma unroll
            for (int nf = 0; nf < 4; ++nf)
                acc[mf][nf] = __builtin_amdgcn_mfma_f32_16x16x32_bf16(
                    av[mf], bv[nf], acc[mf][nf], 0, 0, 0);
        __builtin_amdgcn_s_setprio(0);
    }

    // epilogue: per-wave LDS transpose (stride 68 floats), coalesced stores.
    OutT* Cb = C + sC * bz + sSplit * sp;
    __syncthreads();   // full drain once; epi overlays stage region
    float* lws = (float*)(smem_raw) + (size_t)w * 1088;
    const int lr = lane >> 4;
    const int lc = lane & 15;
#pragma unroll
    for (int mf = 0; mf < 8; ++mf) {
#pragma unroll
        for (int nf = 0; nf < 4; ++nf)
#pragma unroll
            for (int v = 0; v < 4; ++v)
                lws[(q * 4 + v) * 68 + nf * 16 + col] = acc[mf][nf][v];
#pragma unroll
        for (int p = 0; p < 4; ++p) {
            f32x4 t = *(const f32x4*)&lws[(p * 4 + lr) * 68 + lc * 4];
            int row  = tileM + wm * 128 + mf * 16 + p * 4 + lr;
            int colg = tileN + wn * 64 + lc * 4;
            if constexpr (sizeof(OutT) == 2) {
                u16x4 u;
                u[0] = f2bf(t[0]); u[1] = f2bf(t[1]);
                u[2] = f2bf(t[2]); u[3] = f2bf(t[3]);
                *(u16x4*)&Cb[(size_t)row * ldc + colg] = u;
            } else {
                *(f32x4*)&Cb[(size_t)row * ldc + colg] = t;
            }
        }
        // per-wave epi slice is private; no inter-mf barrier needed
    }
}

extern "C" void kernel_launch(void* const* d_in, const int* in_sizes, int n_in,
                              void* d_out, int out_size, void* d_ws, size_t ws_size,
                              hipStream_t stream) {
    const float* X = (const float*)d_in[0];   // [4,4096,1024]
    const float* W = (const float*)d_in[1];   // [1024,1024]
    float* out = (float*)d_out;               // [4,4096,1024] fp32

    char* ws = (char*)d_ws;
    unsigned short* Xb = (unsigned short*)(ws);              // 33,554,432  [b][s][h]
    unsigned short* XT = (unsigned short*)(ws + 33554432);   // 33,554,432  [b][h][s]
    unsigned short* WT = (unsigned short*)(ws + 67108864);   //  2,097,152  [h'][o]
    unsigned short* G  = (unsigned short*)(ws + 69206016);   //  8,388,608  [b][o][h]
    unsigned short* MT = (unsigned short*)(ws + 77594624);   //  8,388,608  [b][h''][h]
    // Scratch (reused serially): Gpart then MTpart, each [sp(4)][b][1024][1024]
    unsigned short* Gpart  = (unsigned short*)(ws + 85983232); // 16,777,216
    unsigned short* MTpart = (unsigned short*)(ws + 85983232); // 16,777,216
    // high-water: 102,760,448 bytes < 153,092,096 proven available

    const size_t sBH = (size_t)B_DIM * H_DIM * H_DIM;

    // 1) casts + transposes
    cast_x_kernel<<<dim3(H_DIM / 64, S_DIM / 64, B_DIM), dim3(16, 16), 0, stream>>>(X, Xb, XT);
    cast_w_kernel<<<dim3(H_DIM / 32, H_DIM / 32, 1), dim3(32, 8), 0, stream>>>(W, WT);

    // 2) G_b = XT_b @ XT_b^T, full symmetric, split-K=4 (Ksub=1024, T=32).
    gemm_d10_kernel<unsigned short, 4><<<dim3(4, 4, B_DIM * 4), 512, 131072, stream>>>(
        XT, XT, Gpart, S_DIM, S_DIM, S_DIM, H_DIM,
        (size_t)H_DIM * S_DIM, (size_t)H_DIM * S_DIM, (size_t)H_DIM * H_DIM, sBH);
    reduce_cast_u16_kernel<4><<<dim3(sBH / 8 / 256), 256, 0, stream>>>(Gpart, G, sBH);

    // 3) MT_b = G_b @ WT^T, split-K=4 (Ksub=256, T=8)
    gemm_d10_kernel<unsigned short, 4><<<dim3(4, 4, B_DIM * 4), 512, 131072, stream>>>(
        G, WT, MTpart, H_DIM, H_DIM, H_DIM, H_DIM,
        (size_t)H_DIM * H_DIM, (size_t)0, (size_t)H_DIM * H_DIM, sBH);
    reduce_cast_u16_kernel<4><<<dim3(sBH / 8 / 256), 256, 0, stream>>>(MTpart, MT, sBH);

    // 4) att_b = Xb_b @ MT_b^T  [4096x1024], K=1024 (T=32), fp32 out.
    //    grid (16,4,4) = 256 blocks = 1/CU exactly.
    gemm_d10_kernel<float, 1><<<dim3(S_DIM / 256, H_DIM / 256, B_DIM), 512, 131072, stream>>>(
        Xb, MT, out, H_DIM, H_DIM, H_DIM, H_DIM,
        (size_t)S_DIM * H_DIM, (size_t)H_DIM * H_DIM, (size_t)S_DIM * H_DIM, 0);
}